// Round 5
// baseline (113.810 us; speedup 1.0000x reference)
//
#include <hip/hip_runtime.h>
#include <hip/hip_bf16.h>

#define N_ROWS 8192
#define DIM 128

typedef short v8s __attribute__((ext_vector_type(8)));   // 8 bf16 (4 VGPRs) MFMA A/B frag
typedef float v4f __attribute__((ext_vector_type(4)));   // MFMA C/D frag

constexpr int NS = 32;                // j-splits (blockIdx.y): 2048 blocks = 8/CU = 32 waves/CU
constexpr int CW = N_ROWS / NS;       // 256 j-rows per split
constexpr int NSLOT = NS;             // partial slots (one per j-split)
constexpr float THRESH = 0.25f;       // sqrt(sqrt(d^2)) + 1e-8 < 0.5  <=>  |d| < 0.25
constexpr float C1 = 14.426950408889634f;  // 10*log2(e): exp(10*dot-10) = 2^(C1*dot - C1)

__device__ __forceinline__ unsigned short f2bf(float f) {
  __hip_bfloat16 h = __float2bfloat16(f);
  return __builtin_bit_cast(unsigned short, h);
}

// ---------------- kernel 1: L2-normalize rows, cast to bf16 ----------------
__global__ __launch_bounds__(256) void knorm(const float* __restrict__ emb,
                                             unsigned short* __restrict__ ebf) {
  const int row  = blockIdx.x * 4 + (threadIdx.x >> 6);  // one wave per row
  const int lane = threadIdx.x & 63;
  const float2 v = *reinterpret_cast<const float2*>(emb + (size_t)row * DIM + lane * 2);
  float ss = fmaf(v.x, v.x, v.y * v.y);
#pragma unroll
  for (int off = 32; off > 0; off >>= 1) ss += __shfl_xor(ss, off);
  const float rn = 1.0f / sqrtf(ss);
  const unsigned int packed =
      (unsigned int)f2bf(v.x * rn) | ((unsigned int)f2bf(v.y * rn) << 16);
  *reinterpret_cast<unsigned int*>(ebf + (size_t)row * DIM + lane * 2) = packed;
}

// ---------------- kernel 2: fused sim-GEMM + row stats (i = MFMA column) ----------------
// block = 256 threads = 4 waves. Wave w owns 32 i-columns [bx*128 + w*32, +32)
// for the WHOLE kernel (B-frags persistent, 32 VGPR). j sweeps the block's
// 256-row split in 16-row subtiles (A-frags transient). Stats accumulate
// in-lane per i (lane = i via C/D col=lane&15): es/ms/ct = 6 regs.
// VGPR=48 (R4) -> 32-waves/CU cap; NS=32 makes the grid supply exactly that
// (8 blocks/CU). Latency-bound fix is TLP, not ILP: a register double-buffer
// would cross the 64-VGPR occupancy step and halve the cap (R2 lesson).
__global__ __launch_bounds__(256) void kmain(const unsigned short* __restrict__ ebf,
                                             const float* __restrict__ props,
                                             float* __restrict__ part) {
  const int lane = threadIdx.x & 63;
  const int w    = threadIdx.x >> 6;
  const int l15  = lane & 15;
  const int g    = lane >> 4;          // 0..3
  const int i0   = blockIdx.x * 128;   // block i-range
  const int iw0  = i0 + w * 32;        // wave i-range (32 cols)
  const int jbase = blockIdx.y * CW;
  const int kb   = g * 8;              // k offset within a 32-k step

  const int icol0 = iw0 + l15;         // n=0 column for this lane
  const int icol1 = iw0 + 16 + l15;    // n=1 column

  // persistent B-frags: lane holds e[icol][kb..kb+8)
  v8s bfr0[4], bfr1[4];
#pragma unroll
  for (int k = 0; k < 4; ++k) {
    bfr0[k] = *reinterpret_cast<const v8s*>(ebf + (size_t)icol0 * DIM + k * 32 + kb);
    bfr1[k] = *reinterpret_cast<const v8s*>(ebf + (size_t)icol1 * DIM + k * 32 + kb);
  }
  const float pc0 = props[icol0];
  const float pc1 = props[icol1];

  float es0 = 0.f, es1 = 0.f, ms0 = 0.f, ms1 = 0.f, ct0 = 0.f, ct1 = 0.f;
  const int jrl = g * 4;               // lane's local row base in a 16-row subtile

#pragma unroll 2
  for (int jb = 0; jb < CW; jb += 16) {
    const int jrow0 = jbase + jb;
    v8s af[4];
#pragma unroll
    for (int k = 0; k < 4; ++k)
      af[k] = *reinterpret_cast<const v8s*>(
          ebf + (size_t)(jrow0 + l15) * DIM + k * 32 + kb);
    const float4 pj = *reinterpret_cast<const float4*>(props + jrow0 + jrl);

    v4f acc0 = {0.f, 0.f, 0.f, 0.f}, acc1 = {0.f, 0.f, 0.f, 0.f};
#pragma unroll
    for (int k = 0; k < 4; ++k) {
      acc0 = __builtin_amdgcn_mfma_f32_16x16x32_bf16(af[k], bfr0[k], acc0, 0, 0, 0);
      acc1 = __builtin_amdgcn_mfma_f32_16x16x32_bf16(af[k], bfr1[k], acc1, 0, 0, 0);
    }

    const float pjv[4] = {pj.x, pj.y, pj.z, pj.w};
    if ((unsigned)(jrow0 - i0) < 128u) {   // subtile may contain the diagonal
#pragma unroll
      for (int r = 0; r < 4; ++r) {
        const int jr = jrow0 + jrl + r;
        {
          const float dot = acc0[r];
          const bool  neq = (jr != icol0);
          const float ex  = __builtin_amdgcn_exp2f(fmaf(dot, C1, -C1));
          es0 += neq ? ex : 0.f;
          const float mskf = (neq && (fabsf(pc0 - pjv[r]) < THRESH)) ? 1.f : 0.f;
          ct0 += mskf;
          ms0 = fmaf(mskf, dot, ms0);
        }
        {
          const float dot = acc1[r];
          const bool  neq = (jr != icol1);
          const float ex  = __builtin_amdgcn_exp2f(fmaf(dot, C1, -C1));
          es1 += neq ? ex : 0.f;
          const float mskf = (neq && (fabsf(pc1 - pjv[r]) < THRESH)) ? 1.f : 0.f;
          ct1 += mskf;
          ms1 = fmaf(mskf, dot, ms1);
        }
      }
    } else {
#pragma unroll
      for (int r = 0; r < 4; ++r) {
        {
          const float dot = acc0[r];
          es0 += __builtin_amdgcn_exp2f(fmaf(dot, C1, -C1));
          const float mskf = (fabsf(pc0 - pjv[r]) < THRESH) ? 1.f : 0.f;
          ct0 += mskf;
          ms0 = fmaf(mskf, dot, ms0);
        }
        {
          const float dot = acc1[r];
          es1 += __builtin_amdgcn_exp2f(fmaf(dot, C1, -C1));
          const float mskf = (fabsf(pc1 - pjv[r]) < THRESH) ? 1.f : 0.f;
          ct1 += mskf;
          ms1 = fmaf(mskf, dot, ms1);
        }
      }
    }
  }

  // sum the 4 g-groups (lanes ^16, ^32); then lanes g==0 hold full stats for their i
#pragma unroll
  for (int off = 16; off <= 32; off <<= 1) {
    es0 += __shfl_xor(es0, off);  es1 += __shfl_xor(es1, off);
    ms0 += __shfl_xor(ms0, off);  ms1 += __shfl_xor(ms1, off);
    ct0 += __shfl_xor(ct0, off);  ct1 += __shfl_xor(ct1, off);
  }

  if (g == 0) {
    float* p0 = part + (size_t)blockIdx.y * 3 * N_ROWS;   // slot = j-split; i disjoint per bx
    p0[icol0]              = es0;
    p0[N_ROWS + icol0]     = ms0;
    p0[2 * N_ROWS + icol0] = ct0;
    p0[icol1]              = es1;
    p0[N_ROWS + icol1]     = ms1;
    p0[2 * N_ROWS + icol1] = ct1;
  }
}

// ---------------- kernel 3: per-row finalize + per-block partial sums ----------------
__global__ __launch_bounds__(256) void kreduce(const float* __restrict__ part,
                                               float* __restrict__ bs,
                                               float* __restrict__ bc) {
  const int row = blockIdx.x * 256 + threadIdx.x;
  float es = 0.f, ms = 0.f, ct = 0.f;
#pragma unroll
  for (int sp = 0; sp < NSLOT; ++sp) {
    const float* p0 = part + (size_t)sp * 3 * N_ROWS;
    es += p0[row];
    ms += p0[N_ROWS + row];
    ct += p0[2 * N_ROWS + row];
  }
  const float lse = 10.0f + logf(es);                       // logsumexp, M=10
  const float per = (ct * lse - 10.0f * ms) / fmaxf(ct, 1.0f);
  float val = (ct > 0.f) ? per : 0.f;
  float vld = (ct > 0.f) ? 1.f : 0.f;
#pragma unroll
  for (int off = 32; off > 0; off >>= 1) {
    val += __shfl_xor(val, off);
    vld += __shfl_xor(vld, off);
  }
  __shared__ float sv[4], sc[4];
  const int wid = threadIdx.x >> 6;
  if ((threadIdx.x & 63) == 0) { sv[wid] = val; sc[wid] = vld; }
  __syncthreads();
  if (threadIdx.x == 0) {
    bs[blockIdx.x] = sv[0] + sv[1] + sv[2] + sv[3];
    bc[blockIdx.x] = sc[0] + sc[1] + sc[2] + sc[3];
  }
}

// ---------------- kernel 4: final scalar ----------------
__global__ __launch_bounds__(64) void kfin(const float* __restrict__ bs,
                                           const float* __restrict__ bc,
                                           float* __restrict__ out) {
  const int l = threadIdx.x;
  float s = (l < 32) ? bs[l] : 0.f;
  float c = (l < 32) ? bc[l] : 0.f;
#pragma unroll
  for (int off = 32; off > 0; off >>= 1) {
    s += __shfl_xor(s, off);
    c += __shfl_xor(c, off);
  }
  if (l == 0) out[0] = (c > 0.f) ? (s / c) : 0.f;
}

extern "C" void kernel_launch(void* const* d_in, const int* in_sizes, int n_in,
                              void* d_out, int out_size, void* d_ws, size_t ws_size,
                              hipStream_t stream) {
  const float* emb   = (const float*)d_in[0];
  const float* props = (const float*)d_in[1];
  float* out = (float*)d_out;

  // ws layout: [0, 2MB) bf16 normalized embeddings; then NSLOT*3*N f32 partials; then 64 f32
  unsigned short* ebf = (unsigned short*)d_ws;
  const size_t EBF_BYTES  = (size_t)N_ROWS * DIM * 2;
  const size_t PART_BYTES = (size_t)NSLOT * 3 * N_ROWS * 4;
  float* part = (float*)((char*)d_ws + EBF_BYTES);
  float* bs   = (float*)((char*)d_ws + EBF_BYTES + PART_BYTES);
  float* bc   = bs + 32;

  knorm<<<N_ROWS / 4, 256, 0, stream>>>(emb, ebf);
  kmain<<<dim3(N_ROWS / 128, NS), 256, 0, stream>>>(ebf, props, part);
  kreduce<<<N_ROWS / 256, 256, 0, stream>>>(part, bs, bc);
  kfin<<<1, 64, 0, stream>>>(bs, bc, out);
}

// Round 6
// 46.899 us; speedup vs baseline: 2.4267x; 2.4267x over previous
//
#include <hip/hip_runtime.h>
#include <hip/hip_bf16.h>

#define N_ROWS 8192
#define DIM 128

typedef short v8s __attribute__((ext_vector_type(8)));   // 8 bf16 (4 VGPRs) MFMA A/B frag
typedef float v4f __attribute__((ext_vector_type(4)));   // MFMA C/D frag
typedef unsigned int u32;

constexpr int NS = 16;                // j-splits (blockIdx.y): 1024 blocks = 4/CU
constexpr int CW = N_ROWS / NS;       // 512 j-rows per split
constexpr int NSLOT = NS;             // partial slots (one per j-split)
constexpr int TILE_J = 64;            // LDS-staged j-rows per tile
constexpr int NTILE = CW / TILE_J;    // 8 tiles per block
constexpr int TILE_BYTES = TILE_J * DIM * 2;  // 16 KB
constexpr float THRESH = 0.25f;       // sqrt(sqrt(d^2)) + 1e-8 < 0.5  <=>  |d| < 0.25
constexpr float C1 = 14.426950408889634f;  // 10*log2(e): exp(10*dot-10) = 2^(C1*dot - C1)

// global->LDS async copy; size must be a literal (macro keeps it one).
#define GLDS(gptr, lptr, sz)                                                   \
  __builtin_amdgcn_global_load_lds(                                            \
      (const __attribute__((address_space(1))) u32*)(gptr),                    \
      (__attribute__((address_space(3))) u32*)(lptr), sz, 0, 0)

__device__ __forceinline__ unsigned short f2bf(float f) {
  __hip_bfloat16 h = __float2bfloat16(f);
  return __builtin_bit_cast(unsigned short, h);
}

// ---------------- kernel 1: L2-normalize rows, cast to bf16 ----------------
__global__ __launch_bounds__(256) void knorm(const float* __restrict__ emb,
                                             unsigned short* __restrict__ ebf) {
  const int row  = blockIdx.x * 4 + (threadIdx.x >> 6);  // one wave per row
  const int lane = threadIdx.x & 63;
  const float2 v = *reinterpret_cast<const float2*>(emb + (size_t)row * DIM + lane * 2);
  float ss = fmaf(v.x, v.x, v.y * v.y);
#pragma unroll
  for (int off = 32; off > 0; off >>= 1) ss += __shfl_xor(ss, off);
  const float rn = 1.0f / sqrtf(ss);
  const unsigned int packed =
      (unsigned int)f2bf(v.x * rn) | ((unsigned int)f2bf(v.y * rn) << 16);
  *reinterpret_cast<unsigned int*>(ebf + (size_t)row * DIM + lane * 2) = packed;
}

// ---------------- kernel 2: fused sim-GEMM + row stats ----------------
// block = 4 waves; wave w owns 32 i-columns persistently (B-frags in regs).
// j sweeps the block's 512-row split in LDS-staged 64-row tiles (double-
// buffered, global_load_lds w=16). A-tile shared by all 4 waves -> 4x L2
// traffic cut vs R4/R5 (which was TA/L2-request bound: VALUBusy 25%).
// Swizzle per rule #21: linear LDS dest, XOR-preswizzled global source,
// same XOR on ds_read (byte ^= (row&7)<<4) -> no 16-way bank conflict.
__global__ __launch_bounds__(256) void kmain(const unsigned short* __restrict__ ebf,
                                             const float* __restrict__ props,
                                             float* __restrict__ part) {
  const int lane = threadIdx.x & 63;
  const int w    = threadIdx.x >> 6;
  const int l15  = lane & 15;
  const int g    = lane >> 4;          // 0..3
  const int i0   = blockIdx.x * 128;   // block i-range
  const int iw0  = i0 + w * 32;        // wave i-range (32 cols)
  const int jbase = blockIdx.y * CW;
  const int kb   = g * 8;              // k element offset within a 32-k step

  __shared__ __align__(1024) char sA[2 * TILE_BYTES + CW * 4];
  char* sprops = sA + 2 * TILE_BYTES;

  const int icol0 = iw0 + l15;         // n=0 column for this lane
  const int icol1 = iw0 + 16 + l15;    // n=1 column

  // persistent B-frags: lane holds e[icol][kb..kb+8)
  v8s bfr0[4], bfr1[4];
#pragma unroll
  for (int k = 0; k < 4; ++k) {
    bfr0[k] = *reinterpret_cast<const v8s*>(ebf + (size_t)icol0 * DIM + k * 32 + kb);
    bfr1[k] = *reinterpret_cast<const v8s*>(ebf + (size_t)icol1 * DIM + k * 32 + kb);
  }
  const float pc0 = props[icol0];
  const float pc1 = props[icol1];

  // stage props[jbase .. +512) into LDS (2 rounds x 4B/thread)
#pragma unroll
  for (int r = 0; r < 2; ++r)
    GLDS(props + jbase + r * 256 + w * 64 + lane, sprops + r * 1024 + w * 256, 4);

  // stage one 64-row A-tile: 4 issues/thread; LDS linear, source pre-swizzled
  auto stageA = [&](int buf, int tile) {
    const int jrow0 = jbase + tile * TILE_J;
    char* base = sA + buf * TILE_BYTES;
#pragma unroll
    for (int q = 0; q < 4; ++q) {
      const int row  = q * 16 + w * 4 + g;               // LDS row this lane-group fills
      const int colb = (l15 << 4) ^ ((row & 7) << 4);    // pre-swizzled source byte-col
      GLDS(ebf + (size_t)(jrow0 + row) * DIM + (colb >> 1),
           base + q * 4096 + w * 1024, 16);
    }
  };

  float es0 = 0.f, es1 = 0.f, ms0 = 0.f, ms1 = 0.f, ct0 = 0.f, ct1 = 0.f;

  stageA(0, 0);
  __syncthreads();                     // vmcnt(0) drain: tile0 + props ready

  int cur = 0;
  for (int t = 0; t < NTILE; ++t) {
    if (t + 1 < NTILE) stageA(cur ^ 1, t + 1);   // prefetch overlaps compute

    char* base = sA + cur * TILE_BYTES;
    const int swz = (l15 & 7) << 4;
#pragma unroll
    for (int s = 0; s < 4; ++s) {
      const int jrow0 = jbase + t * TILE_J + s * 16;
      const int row   = s * 16 + l15;
      v8s af[4];
#pragma unroll
      for (int k = 0; k < 4; ++k)
        af[k] = *reinterpret_cast<const v8s*>(base + row * 256 + ((k * 64 + g * 16) ^ swz));
      const float4 pj = *reinterpret_cast<const float4*>(sprops + t * 256 + s * 64 + g * 16);

      v4f acc0 = {0.f, 0.f, 0.f, 0.f}, acc1 = {0.f, 0.f, 0.f, 0.f};
#pragma unroll
      for (int k = 0; k < 4; ++k) {
        acc0 = __builtin_amdgcn_mfma_f32_16x16x32_bf16(af[k], bfr0[k], acc0, 0, 0, 0);
        acc1 = __builtin_amdgcn_mfma_f32_16x16x32_bf16(af[k], bfr1[k], acc1, 0, 0, 0);
      }

      const float pjv[4] = {pj.x, pj.y, pj.z, pj.w};
      if ((unsigned)(jrow0 - i0) < 128u) {   // subtile may contain the diagonal
#pragma unroll
        for (int r = 0; r < 4; ++r) {
          const int jr = jrow0 + g * 4 + r;
          {
            const float dot = acc0[r];
            const bool  neq = (jr != icol0);
            const float ex  = __builtin_amdgcn_exp2f(fmaf(dot, C1, -C1));
            es0 += neq ? ex : 0.f;
            const float mskf = (neq && (fabsf(pc0 - pjv[r]) < THRESH)) ? 1.f : 0.f;
            ct0 += mskf;
            ms0 = fmaf(mskf, dot, ms0);
          }
          {
            const float dot = acc1[r];
            const bool  neq = (jr != icol1);
            const float ex  = __builtin_amdgcn_exp2f(fmaf(dot, C1, -C1));
            es1 += neq ? ex : 0.f;
            const float mskf = (neq && (fabsf(pc1 - pjv[r]) < THRESH)) ? 1.f : 0.f;
            ct1 += mskf;
            ms1 = fmaf(mskf, dot, ms1);
          }
        }
      } else {
#pragma unroll
        for (int r = 0; r < 4; ++r) {
          {
            const float dot = acc0[r];
            es0 += __builtin_amdgcn_exp2f(fmaf(dot, C1, -C1));
            const float mskf = (fabsf(pc0 - pjv[r]) < THRESH) ? 1.f : 0.f;
            ct0 += mskf;
            ms0 = fmaf(mskf, dot, ms0);
          }
          {
            const float dot = acc1[r];
            es1 += __builtin_amdgcn_exp2f(fmaf(dot, C1, -C1));
            const float mskf = (fabsf(pc1 - pjv[r]) < THRESH) ? 1.f : 0.f;
            ct1 += mskf;
            ms1 = fmaf(mskf, dot, ms1);
          }
        }
      }
    }
    __syncthreads();   // drains vmcnt(0): next tile staged; all reads of cur done
    cur ^= 1;
  }

  // sum the 4 g-groups (lanes ^16, ^32); then lanes g==0 hold full stats for their i
#pragma unroll
  for (int off = 16; off <= 32; off <<= 1) {
    es0 += __shfl_xor(es0, off);  es1 += __shfl_xor(es1, off);
    ms0 += __shfl_xor(ms0, off);  ms1 += __shfl_xor(ms1, off);
    ct0 += __shfl_xor(ct0, off);  ct1 += __shfl_xor(ct1, off);
  }

  if (g == 0) {
    float* p0 = part + (size_t)blockIdx.y * 3 * N_ROWS;   // slot = j-split; i disjoint per bx
    p0[icol0]              = es0;
    p0[N_ROWS + icol0]     = ms0;
    p0[2 * N_ROWS + icol0] = ct0;
    p0[icol1]              = es1;
    p0[N_ROWS + icol1]     = ms1;
    p0[2 * N_ROWS + icol1] = ct1;
  }
}

// ---------------- kernel 3: per-row finalize + per-block partial sums ----------------
__global__ __launch_bounds__(256) void kreduce(const float* __restrict__ part,
                                               float* __restrict__ bs,
                                               float* __restrict__ bc) {
  const int row = blockIdx.x * 256 + threadIdx.x;
  float es = 0.f, ms = 0.f, ct = 0.f;
#pragma unroll
  for (int sp = 0; sp < NSLOT; ++sp) {
    const float* p0 = part + (size_t)sp * 3 * N_ROWS;
    es += p0[row];
    ms += p0[N_ROWS + row];
    ct += p0[2 * N_ROWS + row];
  }
  const float lse = 10.0f + logf(es);                       // logsumexp, M=10
  const float per = (ct * lse - 10.0f * ms) / fmaxf(ct, 1.0f);
  float val = (ct > 0.f) ? per : 0.f;
  float vld = (ct > 0.f) ? 1.f : 0.f;
#pragma unroll
  for (int off = 32; off > 0; off >>= 1) {
    val += __shfl_xor(val, off);
    vld += __shfl_xor(vld, off);
  }
  __shared__ float sv[4], sc[4];
  const int wid = threadIdx.x >> 6;
  if ((threadIdx.x & 63) == 0) { sv[wid] = val; sc[wid] = vld; }
  __syncthreads();
  if (threadIdx.x == 0) {
    bs[blockIdx.x] = sv[0] + sv[1] + sv[2] + sv[3];
    bc[blockIdx.x] = sc[0] + sc[1] + sc[2] + sc[3];
  }
}

// ---------------- kernel 4: final scalar ----------------
__global__ __launch_bounds__(64) void kfin(const float* __restrict__ bs,
                                           const float* __restrict__ bc,
                                           float* __restrict__ out) {
  const int l = threadIdx.x;
  float s = (l < 32) ? bs[l] : 0.f;
  float c = (l < 32) ? bc[l] : 0.f;
#pragma unroll
  for (int off = 32; off > 0; off >>= 1) {
    s += __shfl_xor(s, off);
    c += __shfl_xor(c, off);
  }
  if (l == 0) out[0] = (c > 0.f) ? (s / c) : 0.f;
}

extern "C" void kernel_launch(void* const* d_in, const int* in_sizes, int n_in,
                              void* d_out, int out_size, void* d_ws, size_t ws_size,
                              hipStream_t stream) {
  const float* emb   = (const float*)d_in[0];
  const float* props = (const float*)d_in[1];
  float* out = (float*)d_out;

  // ws layout: [0, 2MB) bf16 normalized embeddings; then NSLOT*3*N f32 partials; then 64 f32
  unsigned short* ebf = (unsigned short*)d_ws;
  const size_t EBF_BYTES  = (size_t)N_ROWS * DIM * 2;
  const size_t PART_BYTES = (size_t)NSLOT * 3 * N_ROWS * 4;
  float* part = (float*)((char*)d_ws + EBF_BYTES);
  float* bs   = (float*)((char*)d_ws + EBF_BYTES + PART_BYTES);
  float* bc   = bs + 32;

  knorm<<<N_ROWS / 4, 256, 0, stream>>>(emb, ebf);
  kmain<<<dim3(N_ROWS / 128, NS), 256, 0, stream>>>(ebf, props, part);
  kreduce<<<N_ROWS / 256, 256, 0, stream>>>(part, bs, bc);
  kfin<<<1, 64, 0, stream>>>(bs, bc, out);
}